// Round 4
// baseline (2222.999 us; speedup 1.0000x reference)
//
#include <hip/hip_runtime.h>
#include <hip/hip_bf16.h>

// TSP GNN: input proj -> TransformerConv(1 head) -> 3x GatedGCN -> edge MLP score.
// All fp32 this round. Key algebraic optimizations:
//  - h[row]@W computed as (h@W)[row]  (node GEMM + gather, not edge GEMM)
//  - e@gWE collapsed: e = attr*W_edge_row + b_edge (rank-1) => attr*uE + cE
//    (all 3 layers' uE/cE computed in one upfront launch)
//  - CSR (by target col) built per call for atomics-free aggregation
//  - 4 independent GEMMs per stage batched into one launch (gridDim.z=4)
//  - edge scoring: one block per 64 edges, j-tile loop in-kernel, no atomics
//  - GEMM LDS: As stored k-major ([32][68], 272B rows, 16B-aligned) so the
//    inner loop is 2x ds_read_b128 (~24 cyc) vs 32 cyc of FMA -> compute-bound

#define HD 300
#define GBM 64
#define GBN 64
#define GBK 32

// ---------------- CSR build ----------------
__global__ void zero_kernel(int* p, int n) {
    int i = blockIdx.x * 256 + threadIdx.x;
    if (i < n) p[i] = 0;
}

__global__ void count_kernel(const int* __restrict__ ei, int* __restrict__ counts, int E) {
    int e = blockIdx.x * 256 + threadIdx.x;
    if (e < E) atomicAdd(&counts[ei[E + e]], 1);   // col = target
}

__global__ __launch_bounds__(1024) void scan_kernel(const int* __restrict__ counts,
                                                    int* __restrict__ offs, int n) {
    // single block, 1024 threads
    __shared__ int sums[1024];
    int tid = threadIdx.x;
    int chunk = (n + 1023) / 1024;
    int s0 = tid * chunk;
    int s1 = min(s0 + chunk, n);
    int local = 0;
    for (int i = s0; i < s1; ++i) local += counts[i];
    sums[tid] = local;
    __syncthreads();
    for (int d = 1; d < 1024; d <<= 1) {
        int t = (tid >= d) ? sums[tid - d] : 0;
        __syncthreads();
        sums[tid] += t;
        __syncthreads();
    }
    int prefix = sums[tid] - local;  // exclusive
    int run = prefix;
    for (int i = s0; i < s1; ++i) { offs[i] = run; run += counts[i]; }
    if (tid == 1023) offs[n] = sums[1023];
}

__global__ void fill_kernel(const int* __restrict__ ei, const int* __restrict__ offs,
                            int* __restrict__ cursor, int* __restrict__ eids, int E) {
    int e = blockIdx.x * 256 + threadIdx.x;
    if (e < E) {
        int c = ei[E + e];
        int p = atomicAdd(&cursor[c], 1);
        eids[offs[c] + p] = e;
    }
}

// ---------------- node embed ----------------
__global__ void embed_kernel(const float* __restrict__ x, const float* __restrict__ W_in,
                             const float* __restrict__ b_in, float* __restrict__ h, int total) {
    int idx = blockIdx.x * 256 + threadIdx.x;
    if (idx < total) {
        int n = idx / HD;
        int j = idx - n * HD;
        h[idx] = x[n * 2] * W_in[j] + x[n * 2 + 1] * W_in[HD + j] + b_in[j];
    }
}

// ---------------- GEMM body: C[M,300] = A[M,300] @ W[300,300] + bias ----------------
// As is k-major [GBK][GBM+4]: row = 68 floats = 272 B (16B-aligned), so both
// operand reads in the inner loop are single ds_read_b128.
__device__ __forceinline__ void gemm_body(const float* __restrict__ A,
                                          const float* __restrict__ W,
                                          const float* __restrict__ bias,
                                          float* __restrict__ C, int M) {
    __shared__ float As[GBK][GBM + 4];
    __shared__ float Ws[GBK][GBN];
    int m0 = blockIdx.x * GBM;
    int j0 = blockIdx.y * GBN;
    int tid = threadIdx.x;
    int tx = tid & 15, ty = tid >> 4;
    float acc[4][4] = {};
    for (int k0 = 0; k0 < HD; k0 += GBK) {
        // A tile: 512 float4 loads, written transposed to k-major LDS
        #pragma unroll
        for (int r = 0; r < 2; ++r) {
            int f4 = tid + r * 256;
            int m = f4 >> 3, kc = (f4 & 7) * 4;
            int gm = m0 + m, gk = k0 + kc;
            float4 v = make_float4(0.f, 0.f, 0.f, 0.f);
            if (gm < M) {
                if (gk + 3 < HD) v = *(const float4*)(A + (size_t)gm * HD + gk);
                else {
                    float t[4] = {0.f, 0.f, 0.f, 0.f};
                    for (int u = 0; u < 4; ++u) if (gk + u < HD) t[u] = A[(size_t)gm * HD + gk + u];
                    v = make_float4(t[0], t[1], t[2], t[3]);
                }
            }
            As[kc + 0][m] = v.x; As[kc + 1][m] = v.y; As[kc + 2][m] = v.z; As[kc + 3][m] = v.w;
        }
        // W tile [32][64] : 512 float4, 2 per thread
        #pragma unroll
        for (int r = 0; r < 2; ++r) {
            int f4 = tid + r * 256;
            int kk = f4 >> 4, jc = (f4 & 15) * 4;
            int gk = k0 + kk, gj = j0 + jc;
            float4 v = make_float4(0.f, 0.f, 0.f, 0.f);
            if (gk < HD) {
                if (gj + 3 < HD) v = *(const float4*)(W + (size_t)gk * HD + gj);
                else {
                    float t[4] = {0.f, 0.f, 0.f, 0.f};
                    for (int u = 0; u < 4; ++u) if (gj + u < HD) t[u] = W[(size_t)gk * HD + gj + u];
                    v = make_float4(t[0], t[1], t[2], t[3]);
                }
            }
            Ws[kk][jc + 0] = v.x; Ws[kk][jc + 1] = v.y; Ws[kk][jc + 2] = v.z; Ws[kk][jc + 3] = v.w;
        }
        __syncthreads();
        #pragma unroll
        for (int k = 0; k < GBK; ++k) {
            float4 a = *(const float4*)&As[k][ty * 4];
            float4 w = *(const float4*)&Ws[k][tx * 4];
            acc[0][0] += a.x * w.x; acc[0][1] += a.x * w.y; acc[0][2] += a.x * w.z; acc[0][3] += a.x * w.w;
            acc[1][0] += a.y * w.x; acc[1][1] += a.y * w.y; acc[1][2] += a.y * w.z; acc[1][3] += a.y * w.w;
            acc[2][0] += a.z * w.x; acc[2][1] += a.z * w.y; acc[2][2] += a.z * w.z; acc[2][3] += a.z * w.w;
            acc[3][0] += a.w * w.x; acc[3][1] += a.w * w.y; acc[3][2] += a.w * w.z; acc[3][3] += a.w * w.w;
        }
        __syncthreads();
    }
    #pragma unroll
    for (int r = 0; r < 4; ++r) {
        int gm = m0 + ty * 4 + r;
        if (gm >= M) continue;
        #pragma unroll
        for (int c = 0; c < 4; ++c) {
            int gj = j0 + tx * 4 + c;
            if (gj < HD) C[(size_t)gm * HD + gj] = acc[r][c] + bias[gj];
        }
    }
}

// 4 independent GEMMs (same A) in one launch; blockIdx.z selects weights/output.
__global__ __launch_bounds__(256) void gemm_bias4(const float* __restrict__ A,
                                                  const float* W0, const float* W1,
                                                  const float* W2, const float* W3,
                                                  const float* b0, const float* b1,
                                                  const float* b2, const float* b3,
                                                  float* C0, float* C1, float* C2, float* C3,
                                                  int M) {
    const float* W; const float* b; float* C;
    switch (blockIdx.z) {
        case 0:  W = W0; b = b0; C = C0; break;
        case 1:  W = W1; b = b1; C = C1; break;
        case 2:  W = W2; b = b2; C = C2; break;
        default: W = W3; b = b3; C = C3; break;
    }
    gemm_body(A, W, b, C, M);
}

// ---------------- attention aggregate (block per target node) ----------------
__global__ __launch_bounds__(256) void attn_agg(const float* __restrict__ q,
                                                const float* __restrict__ k,
                                                const float* __restrict__ v,
                                                const float* __restrict__ sk,
                                                const int* __restrict__ ei,
                                                const int* __restrict__ offs,
                                                const int* __restrict__ eids,
                                                float* __restrict__ hout) {
    int n = blockIdx.x;
    int tid = threadIdx.x;
    __shared__ float qs[HD];
    __shared__ float lg[64];
    __shared__ int ss[64];
    __shared__ float sm_m, sm_s, sm_scale;
    for (int j = tid; j < HD; j += 256) qs[j] = q[(size_t)n * HD + j];
    if (tid == 0) { sm_m = -1e30f; sm_s = 0.f; }
    __syncthreads();
    int start = offs[n], end = offs[n + 1];
    float acc0 = 0.f, acc1 = 0.f;
    const float rs = 1.0f / sqrtf((float)HD);
    int wv = tid >> 6, ln = tid & 63;
    for (int c0 = start; c0 < end; c0 += 64) {
        int cnt = min(64, end - c0);
        // logits (4 waves, one edge per wave at a time)
        for (int i = wv; i < cnt; i += 4) {
            int eid = eids[c0 + i];
            int src = ei[eid];  // row (source)
            float p = 0.f;
            const float* kr = k + (size_t)src * HD;
            for (int j = ln; j < HD; j += 64) p += qs[j] * kr[j];
            p += __shfl_xor(p, 32); p += __shfl_xor(p, 16); p += __shfl_xor(p, 8);
            p += __shfl_xor(p, 4);  p += __shfl_xor(p, 2);  p += __shfl_xor(p, 1);
            if (ln == 0) { lg[i] = p * rs; ss[i] = src; }
        }
        __syncthreads();
        // wave 0: online softmax update
        if (wv == 0) {
            float l = (ln < cnt) ? lg[ln] : -1e30f;
            float mx = l;
            for (int d = 32; d; d >>= 1) mx = fmaxf(mx, __shfl_xor(mx, d));
            float m_old = sm_m;
            float m_new = fmaxf(m_old, mx);
            float w = (ln < cnt) ? __expf(l - m_new) : 0.f;
            float sum = w;
            for (int d = 32; d; d >>= 1) sum += __shfl_xor(sum, d);
            if (ln == 0) {
                sm_scale = __expf(m_old - m_new);
                sm_s = sm_s * sm_scale + sum;
                sm_m = m_new;
            }
            if (ln < cnt) lg[ln] = w;
        }
        __syncthreads();
        float scale = sm_scale;
        acc0 *= scale; acc1 *= scale;
        for (int i = 0; i < cnt; ++i) {
            float w = lg[i];
            const float* vr = v + (size_t)ss[i] * HD;
            acc0 += w * vr[tid];
            if (tid + 256 < HD) acc1 += w * vr[tid + 256];
        }
        __syncthreads();
    }
    float inv = (end > start) ? 1.0f / sm_s : 0.f;
    size_t base = (size_t)n * HD;
    hout[base + tid] = acc0 * inv + sk[base + tid];
    if (tid + 256 < HD) hout[base + tid + 256] = acc1 * inv + sk[base + tid + 256];
}

// ---------------- uE/cE: rank-1 collapse of e@gWE, all 3 layers at once ----------
__global__ void edge_w_proj(const float* __restrict__ W_edge, const float* __restrict__ b_edge,
                            const float* __restrict__ gWE, const float* __restrict__ gbE,
                            float* __restrict__ uc) {
    int j = blockIdx.x;
    int l = blockIdx.y;
    const float* WE = gWE + (size_t)l * HD * HD;
    const float* bE = gbE + (size_t)l * HD;
    float* ucl = uc + (size_t)l * 2 * HD;
    int ln = threadIdx.x;  // 64
    float pu = 0.f, pc = 0.f;
    for (int kk = ln; kk < HD; kk += 64) {
        float w = WE[(size_t)kk * HD + j];
        pu += W_edge[kk] * w;
        pc += b_edge[kk] * w;
    }
    for (int d = 32; d; d >>= 1) { pu += __shfl_xor(pu, d); pc += __shfl_xor(pc, d); }
    if (ln == 0) { ucl[j] = pu; ucl[HD + j] = pc + bE[j]; }
}

// ---------------- GatedGCN aggregate (block per target node) ----------------
__global__ __launch_bounds__(256) void gated_agg(const float* __restrict__ hA,
                                                 const float* __restrict__ hB,
                                                 const float* __restrict__ hC,
                                                 const float* __restrict__ hR,
                                                 const float* __restrict__ uc,
                                                 const int* __restrict__ ei,
                                                 const float* __restrict__ attr,
                                                 const int* __restrict__ offs,
                                                 const int* __restrict__ eids,
                                                 float* __restrict__ hout) {
    int n = blockIdx.x;
    int tid = threadIdx.x;
    int start = offs[n], end = offs[n + 1];
    size_t base = (size_t)n * HD;
    int j2 = tid + 256;
    bool b2 = j2 < HD;
    float c1 = hC[base + tid], c2 = b2 ? hC[base + j2] : 0.f;
    float u1 = uc[tid],        u2 = b2 ? uc[j2] : 0.f;
    float e1 = uc[HD + tid],   e2 = b2 ? uc[HD + j2] : 0.f;
    float acc1 = 0.f, acc2 = 0.f;
    for (int i = start; i < end; ++i) {
        int eid = eids[i];
        int src = ei[eid];
        float a = attr[eid];
        size_t sb = (size_t)src * HD;
        float t1 = hB[sb + tid] + c1 + a * u1 + e1;
        float s1 = 1.f / (1.f + __expf(-t1));
        acc1 += s1 * hA[sb + tid];
        if (b2) {
            float t2 = hB[sb + j2] + c2 + a * u2 + e2;
            float s2 = 1.f / (1.f + __expf(-t2));
            acc2 += s2 * hA[sb + j2];
        }
    }
    hout[base + tid] = fmaxf(acc1 + hR[base + tid], 0.f);
    if (b2) hout[base + j2] = fmaxf(acc2 + hR[base + j2], 0.f);
}

// ---------------- edge scoring: one block per 64 edges, full j loop, no atomics ----
__global__ __launch_bounds__(256) void score_fused(const float* __restrict__ h,
                                                   const int* __restrict__ ei,
                                                   const float* __restrict__ mW1,
                                                   const float* __restrict__ mb1,
                                                   const float* __restrict__ mW2,
                                                   const float* __restrict__ mb2,
                                                   float* __restrict__ out, int E) {
    __shared__ float As[GBK][GBM + 4];
    __shared__ float Ws[GBK][GBN];
    __shared__ int rows[64], cols[64];
    int e0 = blockIdx.x * 64;
    int tid = threadIdx.x;
    if (tid < 64) { int e = e0 + tid; rows[tid] = (e < E) ? ei[e] : 0; }
    else if (tid < 128) { int t = tid - 64; int e = e0 + t; cols[t] = (e < E) ? ei[E + e] : 0; }
    __syncthreads();
    int tx = tid & 15, ty = tid >> 4;
    float p[4] = {0.f, 0.f, 0.f, 0.f};

    for (int j0 = 0; j0 < HD; j0 += GBN) {
        float acc[4][4] = {};
        for (int k0 = 0; k0 < HD; k0 += GBK) {
            // |h_row - h_col| tile, written transposed to k-major LDS
            #pragma unroll
            for (int r = 0; r < 2; ++r) {
                int f4 = tid + r * 256;
                int m = f4 >> 3, kc = (f4 & 7) * 4;
                int gk = k0 + kc;
                float4 a = make_float4(0.f, 0.f, 0.f, 0.f), b = a;
                int e = e0 + m;
                if (e < E) {
                    const float* hr = h + (size_t)rows[m] * HD;
                    const float* hc = h + (size_t)cols[m] * HD;
                    if (gk + 3 < HD) {
                        a = *(const float4*)(hr + gk);
                        b = *(const float4*)(hc + gk);
                    } else {
                        float ta[4] = {0.f, 0.f, 0.f, 0.f}, tb[4] = {0.f, 0.f, 0.f, 0.f};
                        for (int u = 0; u < 4; ++u) if (gk + u < HD) { ta[u] = hr[gk + u]; tb[u] = hc[gk + u]; }
                        a = make_float4(ta[0], ta[1], ta[2], ta[3]);
                        b = make_float4(tb[0], tb[1], tb[2], tb[3]);
                    }
                }
                As[kc + 0][m] = fabsf(a.x - b.x);
                As[kc + 1][m] = fabsf(a.y - b.y);
                As[kc + 2][m] = fabsf(a.z - b.z);
                As[kc + 3][m] = fabsf(a.w - b.w);
            }
            // mW1 tile [32][64]
            #pragma unroll
            for (int r = 0; r < 2; ++r) {
                int f4 = tid + r * 256;
                int kk = f4 >> 4, jc = (f4 & 15) * 4;
                int gk = k0 + kk, gj = j0 + jc;
                float4 v = make_float4(0.f, 0.f, 0.f, 0.f);
                if (gk < HD) {
                    if (gj + 3 < HD) v = *(const float4*)(mW1 + (size_t)gk * HD + gj);
                    else {
                        float t[4] = {0.f, 0.f, 0.f, 0.f};
                        for (int u = 0; u < 4; ++u) if (gj + u < HD) t[u] = mW1[(size_t)gk * HD + gj + u];
                        v = make_float4(t[0], t[1], t[2], t[3]);
                    }
                }
                Ws[kk][jc + 0] = v.x; Ws[kk][jc + 1] = v.y; Ws[kk][jc + 2] = v.z; Ws[kk][jc + 3] = v.w;
            }
            __syncthreads();
            #pragma unroll
            for (int k = 0; k < GBK; ++k) {
                float4 a = *(const float4*)&As[k][ty * 4];
                float4 w = *(const float4*)&Ws[k][tx * 4];
                acc[0][0] += a.x * w.x; acc[0][1] += a.x * w.y; acc[0][2] += a.x * w.z; acc[0][3] += a.x * w.w;
                acc[1][0] += a.y * w.x; acc[1][1] += a.y * w.y; acc[1][2] += a.y * w.z; acc[1][3] += a.y * w.w;
                acc[2][0] += a.z * w.x; acc[2][1] += a.z * w.y; acc[2][2] += a.z * w.z; acc[2][3] += a.z * w.w;
                acc[3][0] += a.w * w.x; acc[3][1] += a.w * w.y; acc[3][2] += a.w * w.z; acc[3][3] += a.w * w.w;
            }
            __syncthreads();
        }
        // fold this j-tile into per-edge scalars
        #pragma unroll
        for (int r = 0; r < 4; ++r) {
            #pragma unroll
            for (int c = 0; c < 4; ++c) {
                int gj = j0 + tx * 4 + c;
                if (gj < HD) {
                    float o = fmaxf(acc[r][c] + mb1[gj], 0.f);
                    p[r] += o * mW2[gj];
                }
            }
        }
    }
    // reduce across the 16 tx lanes (within-wave) and store once
    #pragma unroll
    for (int r = 0; r < 4; ++r) {
        float s = p[r];
        s += __shfl_xor(s, 1); s += __shfl_xor(s, 2);
        s += __shfl_xor(s, 4); s += __shfl_xor(s, 8);
        if (tx == 0) {
            int e = e0 + ty * 4 + r;
            if (e < E) out[e] = s + mb2[0];
        }
    }
}

// ---------------- launch ----------------
extern "C" void kernel_launch(void* const* d_in, const int* in_sizes, int n_in,
                              void* d_out, int out_size, void* d_ws, size_t ws_size,
                              hipStream_t stream) {
    const int N = in_sizes[0] / 2;
    const int E = in_sizes[2];
    const int H = HD;

    const float* x      = (const float*)d_in[0];
    const int*   ei     = (const int*)d_in[1];
    const float* attr   = (const float*)d_in[2];
    const float* W_in   = (const float*)d_in[3];
    const float* b_in   = (const float*)d_in[4];
    const float* W_edge = (const float*)d_in[5];
    const float* b_edge = (const float*)d_in[6];
    const float* Wq = (const float*)d_in[7];  const float* bq = (const float*)d_in[8];
    const float* Wk = (const float*)d_in[9];  const float* bk = (const float*)d_in[10];
    const float* Wv = (const float*)d_in[11]; const float* bv = (const float*)d_in[12];
    const float* Wsk = (const float*)d_in[13]; const float* bsk = (const float*)d_in[14];
    const float* gWA = (const float*)d_in[15]; const float* gbA = (const float*)d_in[16];
    const float* gWB = (const float*)d_in[17]; const float* gbB = (const float*)d_in[18];
    const float* gWC = (const float*)d_in[19]; const float* gbC = (const float*)d_in[20];
    const float* gWE = (const float*)d_in[21]; const float* gbE = (const float*)d_in[22];
    const float* gWr = (const float*)d_in[23]; const float* gbr = (const float*)d_in[24];
    const float* mW1 = (const float*)d_in[25]; const float* mb1 = (const float*)d_in[26];
    const float* mW2 = (const float*)d_in[27]; const float* mb2 = (const float*)d_in[28];
    float* out = (float*)d_out;

    size_t NH = (size_t)N * H;
    float* h  = (float*)d_ws;
    float* t0 = h + NH;
    float* t1 = t0 + NH;
    float* t2 = t1 + NH;
    float* t3 = t2 + NH;
    float* uc = t3 + NH;          // 3 layers x 2 x H floats (padded to 2048)
    int* counts = (int*)(uc + 2048);
    int* cursor = counts + N;
    int* offs   = cursor + N;
    int* eids   = offs + (N + 1);

    // CSR build
    zero_kernel<<<(2 * N + 255) / 256, 256, 0, stream>>>(counts, 2 * N);
    count_kernel<<<(E + 255) / 256, 256, 0, stream>>>(ei, counts, E);
    scan_kernel<<<1, 1024, 0, stream>>>(counts, offs, N);
    fill_kernel<<<(E + 255) / 256, 256, 0, stream>>>(ei, offs, cursor, eids, E);

    // input projection
    embed_kernel<<<(N * H + 255) / 256, 256, 0, stream>>>(x, W_in, b_in, h, N * H);

    // rank-1 edge projections for all 3 GatedGCN layers (independent of h)
    edge_w_proj<<<dim3(H, 3), 64, 0, stream>>>(W_edge, b_edge, gWE, gbE, uc);

    dim3 gn((N + GBM - 1) / GBM, (H + GBN - 1) / GBN, 4);
    // TransformerConv: q,k,v,skip in one launch
    gemm_bias4<<<gn, 256, 0, stream>>>(h, Wq, Wk, Wv, Wsk, bq, bk, bv, bsk,
                                       t0, t1, t2, t3, N);
    attn_agg<<<N, 256, 0, stream>>>(t0, t1, t2, t3, ei, offs, eids, h);

    // GatedGCN layers: A,B,C,r in one launch per layer
    for (int l = 0; l < 3; ++l) {
        size_t wo = (size_t)l * H * H;
        size_t bo = (size_t)l * H;
        gemm_bias4<<<gn, 256, 0, stream>>>(h, gWA + wo, gWB + wo, gWC + wo, gWr + wo,
                                           gbA + bo, gbB + bo, gbC + bo, gbr + bo,
                                           t0, t1, t2, t3, N);
        gated_agg<<<N, 256, 0, stream>>>(t0, t1, t2, t3, uc + (size_t)l * 2 * H,
                                         ei, attr, offs, eids, h);
    }

    // edge scoring (no init kernel, no atomics)
    score_fused<<<(E + 63) / 64, 256, 0, stream>>>(h, ei, mW1, mb1, mW2, mb2, out, E);
}